// Round 9
// baseline (610.737 us; speedup 1.0000x reference)
//
#include <hip/hip_runtime.h>

#define NN 50000
#define NE 800000
#define DIN 256
#define DH 128
#define BCAP 64

typedef float f32x4 __attribute__((ext_vector_type(4)));
typedef __bf16 bf16x8 __attribute__((ext_vector_type(8)));
typedef unsigned short u16;
typedef unsigned int u32;

__device__ __forceinline__ u16 f2b(float f) { return __builtin_bit_cast(u16, (__bf16)f); }
__device__ __forceinline__ float lo_f(u32 u) { return (float)__builtin_bit_cast(__bf16, (u16)(u & 0xFFFFu)); }
__device__ __forceinline__ float hi_f(u32 u) { return (float)__builtin_bit_cast(__bf16, (u16)(u >> 16)); }

__device__ __forceinline__ f32x4 mfma16(bf16x8 a, bf16x8 b, f32x4 c) {
    return __builtin_amdgcn_mfma_f32_16x16x32_bf16(a, b, c, 0, 0, 0);
}

// ---------------- merged: weight pre-swizzle (32 blocks) + hist + bucket fill (src, edge_id) ----------------
__global__ void k_prep_fill(const float* __restrict__ w1, const float* __restrict__ w2,
                            const float* __restrict__ wg,
                            u16* __restrict__ w12f, u16* __restrict__ wgf,
                            const int* __restrict__ ei,
                            int* __restrict__ cnt, int2* __restrict__ bucket) {
    int b = blockIdx.x;
    if (b < 32) {
        int t = b * 256 + threadIdx.x;  // 0..8191
        const float* src; u16* dst; int id;
        if (t < 2048)      { src = w1; dst = w12f;          id = t; }
        else if (t < 4096) { src = w2; dst = w12f + 16384;  id = t - 2048; }
        else               { src = wg; dst = wgf;           id = t - 4096; }
        int lane = id & 63, frag = id >> 6;
        int kt = frag >> 3, nt = frag & 7;
        int k0 = kt * 32 + (lane >> 4) * 8, n = nt * 16 + (lane & 15);
        u16 v[8];
#pragma unroll
        for (int j = 0; j < 8; ++j) v[j] = f2b(src[(k0 + j) * 128 + n]);
#pragma unroll
        for (int j = 0; j < 8; ++j) dst[id * 8 + j] = v[j];
    } else {
        int e = (b - 32) * 256 + threadIdx.x;
        int d = ei[NE + e];
        int s = ei[e];
        int pos = atomicAdd(&cnt[d], 1);
        bucket[d * BCAP + pos] = make_int2(s, e);
    }
}

// ---------------- h0pre = (x @ W_gcn) * dinv[row]  (fp32 x -> bf16 MFMA; dinv inline) ----------------
__global__ __launch_bounds__(128) void k_gemm_x(const float* __restrict__ x,
                                                const u16* __restrict__ wgf,
                                                const int* __restrict__ cnt,
                                                u16* __restrict__ h0pre) {
    int wave = threadIdx.x >> 6, lane = threadIdx.x & 63;
    int l15 = lane & 15, q = lane >> 4;
    int rowBase = blockIdx.x * 64 + wave * 32;

    bf16x8 a[2][8];
#pragma unroll
    for (int mi = 0; mi < 2; ++mi) {
        int r = rowBase + mi * 16 + l15; if (r >= NN) r = NN - 1;
        const float* rp = x + (size_t)r * DIN + q * 8;
#pragma unroll
        for (int kt = 0; kt < 8; ++kt) {
            f32x4 f0 = *(const f32x4*)(rp + kt * 32);
            f32x4 f1 = *(const f32x4*)(rp + kt * 32 + 4);
            bf16x8 aa;
#pragma unroll
            for (int j = 0; j < 4; ++j) { aa[j] = (__bf16)f0[j]; aa[j + 4] = (__bf16)f1[j]; }
            a[mi][kt] = aa;
        }
    }
    f32x4 z = {0.f, 0.f, 0.f, 0.f};
    f32x4 acc[2][8];
#pragma unroll
    for (int mi = 0; mi < 2; ++mi)
#pragma unroll
        for (int nt = 0; nt < 8; ++nt) acc[mi][nt] = z;

#pragma unroll
    for (int kt = 0; kt < 8; ++kt)
#pragma unroll
        for (int nt = 0; nt < 8; ++nt) {
            bf16x8 b = *(const bf16x8*)(wgf + ((kt * 8 + nt) * 64 + lane) * 8);
            acc[0][nt] = mfma16(a[0][kt], b, acc[0][nt]);
            acc[1][nt] = mfma16(a[1][kt], b, acc[1][nt]);
        }
#pragma unroll
    for (int mi = 0; mi < 2; ++mi)
#pragma unroll
        for (int rg = 0; rg < 4; ++rg) {
            int r = rowBase + mi * 16 + q * 4 + rg;
            if (r < NN) {
                float dv = rsqrtf((float)cnt[r] + 1.0f);
#pragma unroll
                for (int nt = 0; nt < 8; ++nt)
                    h0pre[r * DH + nt * 16 + l15] = f2b(acc[mi][nt][rg] * dv);
            }
        }
}

// ---------------- GCN aggregate: 8-way ILP over fixed-stride bucket (int2.x = src) ----------------
__global__ __launch_bounds__(256) void k_aggregate(const u16* __restrict__ h0pre,
                                                   const int* __restrict__ cnt,
                                                   const int2* __restrict__ bucket,
                                                   const float* __restrict__ bg,
                                                   u16* __restrict__ hA) {
    int v = blockIdx.x * 4 + (threadIdx.x >> 6);
    int lane = threadIdx.x & 63;
    const u32* h = (const u32*)h0pre;
    u32 su = h[v * 64 + lane];
    float p0[8], p1[8];
#pragma unroll
    for (int k = 0; k < 8; ++k) { p0[k] = 0.f; p1[k] = 0.f; }
    p0[0] = lo_f(su); p1[0] = hi_f(su);  // self-loop (dv^2*h = dv*h0pre folded)
    int deg = cnt[v];
    const int2* bk = bucket + v * BCAP;
    int j = 0;
    for (; j + 8 <= deg; j += 8) {
        int idx[8]; u32 u[8];
#pragma unroll
        for (int k = 0; k < 8; ++k) idx[k] = bk[j + k].x;
#pragma unroll
        for (int k = 0; k < 8; ++k) u[k] = h[idx[k] * 64 + lane];
#pragma unroll
        for (int k = 0; k < 8; ++k) { p0[k] += lo_f(u[k]); p1[k] += hi_f(u[k]); }
    }
    for (; j + 2 <= deg; j += 2) {
        u32 ua = h[bk[j].x * 64 + lane];
        u32 ub = h[bk[j + 1].x * 64 + lane];
        p0[0] += lo_f(ua); p1[0] += hi_f(ua);
        p0[1] += lo_f(ub); p1[1] += hi_f(ub);
    }
    for (; j < deg; ++j) {
        u32 u = h[bk[j].x * 64 + lane];
        p0[0] += lo_f(u); p1[0] += hi_f(u);
    }
#pragma unroll
    for (int k = 4; k >= 1; k >>= 1)
#pragma unroll
        for (int m = 0; m < k; ++m) { p0[m] += p0[m + k]; p1[m] += p1[m + k]; }
    float dv = rsqrtf((float)deg + 1.0f);
    float bg0 = bg[2 * lane], bg1 = bg[2 * lane + 1];
    float a0 = fmaxf(p0[0] * dv + bg0, 0.f);
    float a1 = fmaxf(p1[0] * dv + bg1, 0.f);
    ((u32*)hA)[v * 64 + lane] = (u32)f2b(a0) | ((u32)f2b(a1) << 16);
}

// ---------------- fused node MLP + gh-precompute ----------------
// gh = 0.5 * (relu(relu(hA@W1+b1)@W2+b2) @ W1) + 0.5*b1   (so edge t1 = relu(gh_s + gh_d))
__global__ __launch_bounds__(256) void k_node_mlp(const u16* __restrict__ hA,
                                                  const u16* __restrict__ wf,
                                                  const float* __restrict__ b1,
                                                  const float* __restrict__ b2,
                                                  u16* __restrict__ gh) {
    __shared__ __align__(16) u16 wlds[16384];     // weight buffer (W1 -> W2 -> W1)
    __shared__ __align__(16) u16 sct[4][2176];    // per-wave transpose scratch
    {
        const uint4* s = (const uint4*)wf;
        uint4* d = (uint4*)wlds;
        for (int i = threadIdx.x; i < 2048; i += 256) d[i] = s[i];
    }
    __syncthreads();
    int wave = threadIdx.x >> 6, lane = threadIdx.x & 63;
    int l15 = lane & 15, q = lane >> 4;
    int rowBase = blockIdx.x * 128 + wave * 32;
    u16* sw = sct[wave];

    bf16x8 a[2][4];
#pragma unroll
    for (int mi = 0; mi < 2; ++mi) {
        int r = rowBase + mi * 16 + l15; if (r >= NN) r = NN - 1;
        const u16* rp = hA + r * DH + q * 8;
#pragma unroll
        for (int kt = 0; kt < 4; ++kt) a[mi][kt] = *(const bf16x8*)(rp + kt * 32);
    }
    f32x4 z = {0.f, 0.f, 0.f, 0.f};
    f32x4 acc1[2][8];
#pragma unroll
    for (int mi = 0; mi < 2; ++mi)
#pragma unroll
        for (int nt = 0; nt < 8; ++nt) acc1[mi][nt] = z;
#pragma unroll
    for (int kt = 0; kt < 4; ++kt)
#pragma unroll
        for (int nt = 0; nt < 8; ++nt) {
            bf16x8 b = *(const bf16x8*)(wlds + (kt * 8 + nt) * 512 + lane * 8);
            acc1[0][nt] = mfma16(a[0][kt], b, acc1[0][nt]);
            acc1[1][nt] = mfma16(a[1][kt], b, acc1[1][nt]);
        }
    float bb1[8], bb2[8];
#pragma unroll
    for (int nt = 0; nt < 8; ++nt) { bb1[nt] = b1[nt * 16 + l15]; bb2[nt] = b2[nt * 16 + l15]; }

    bf16x8 a2[2][4];
#pragma unroll
    for (int mi = 0; mi < 2; ++mi) {
#pragma unroll
        for (int nt = 0; nt < 8; ++nt)
#pragma unroll
            for (int rg = 0; rg < 4; ++rg) {
                float v = acc1[mi][nt][rg] + bb1[nt];
                v = v > 0.f ? v : 0.f;
                sw[(q * 4 + rg) * 136 + nt * 16 + l15] = f2b(v);
            }
#pragma unroll
        for (int kt = 0; kt < 4; ++kt)
            a2[mi][kt] = *(const bf16x8*)(sw + l15 * 136 + kt * 32 + q * 8);
    }
    __syncthreads();  // all waves done reading W1
    {
        const uint4* s = (const uint4*)(wf + 16384);
        uint4* d = (uint4*)wlds;
        for (int i = threadIdx.x; i < 2048; i += 256) d[i] = s[i];
    }
    __syncthreads();
    f32x4 acc2[2][8];
#pragma unroll
    for (int mi = 0; mi < 2; ++mi)
#pragma unroll
        for (int nt = 0; nt < 8; ++nt) acc2[mi][nt] = z;
#pragma unroll
    for (int kt = 0; kt < 4; ++kt)
#pragma unroll
        for (int nt = 0; nt < 8; ++nt) {
            bf16x8 b = *(const bf16x8*)(wlds + (kt * 8 + nt) * 512 + lane * 8);
            acc2[0][nt] = mfma16(a2[0][kt], b, acc2[0][nt]);
            acc2[1][nt] = mfma16(a2[1][kt], b, acc2[1][nt]);
        }
    bf16x8 a3[2][4];
#pragma unroll
    for (int mi = 0; mi < 2; ++mi) {
#pragma unroll
        for (int nt = 0; nt < 8; ++nt)
#pragma unroll
            for (int rg = 0; rg < 4; ++rg) {
                float v = acc2[mi][nt][rg] + bb2[nt];
                v = v > 0.f ? v : 0.f;
                sw[(q * 4 + rg) * 136 + nt * 16 + l15] = f2b(v);
            }
#pragma unroll
        for (int kt = 0; kt < 4; ++kt)
            a3[mi][kt] = *(const bf16x8*)(sw + l15 * 136 + kt * 32 + q * 8);
    }
    __syncthreads();  // all waves done reading W2
    {
        const uint4* s = (const uint4*)wf;  // reload W1
        uint4* d = (uint4*)wlds;
        for (int i = threadIdx.x; i < 2048; i += 256) d[i] = s[i];
    }
    __syncthreads();
    f32x4 acc3[2][8];
#pragma unroll
    for (int mi = 0; mi < 2; ++mi)
#pragma unroll
        for (int nt = 0; nt < 8; ++nt) acc3[mi][nt] = z;
#pragma unroll
    for (int kt = 0; kt < 4; ++kt)
#pragma unroll
        for (int nt = 0; nt < 8; ++nt) {
            bf16x8 b = *(const bf16x8*)(wlds + (kt * 8 + nt) * 512 + lane * 8);
            acc3[0][nt] = mfma16(a3[0][kt], b, acc3[0][nt]);
            acc3[1][nt] = mfma16(a3[1][kt], b, acc3[1][nt]);
        }
#pragma unroll
    for (int mi = 0; mi < 2; ++mi)
#pragma unroll
        for (int nt = 0; nt < 8; ++nt)
#pragma unroll
            for (int rg = 0; rg < 4; ++rg) {
                int r = rowBase + mi * 16 + q * 4 + rg;
                if (r < NN)
                    gh[r * DH + nt * 16 + l15] = f2b(0.5f * acc3[mi][nt][rg] + 0.5f * bb1[nt]);
            }
}

// ---------------- edge kernel: dst-grouped via buckets; wave owns 8 dst nodes ----------------
// t1 = relu(gh_src + gh_dst); dst-side gathers hit the same row repeatedly (TA merge).
__global__ __launch_bounds__(256, 3) void k_edge_mlp(const u16* __restrict__ gh,
                                                     const int2* __restrict__ bucket,
                                                     const int* __restrict__ cnt,
                                                     const u16* __restrict__ wf,
                                                     const float* __restrict__ b2,
                                                     const float* __restrict__ ow,
                                                     const float* __restrict__ ob,
                                                     float2* __restrict__ outp) {
    __shared__ __align__(16) u16 wlds[16384];  // W2 only
    {
        const uint4* s = (const uint4*)(wf + 16384);
        uint4* d = (uint4*)wlds;
        for (int i = threadIdx.x; i < 2048; i += 256) d[i] = s[i];
    }
    int wave = threadIdx.x >> 6, lane = threadIdx.x & 63;
    int l15 = lane & 15, q = lane >> 4;
    int dstBase = blockIdx.x * 32 + wave * 8;

    // per-wave 8-dst prefix (exclusive) via shfl
    int c = 0;
    if (lane < 8) { int d = dstBase + lane; c = (d < NN) ? cnt[d] : 0; }
    int s[9]; s[0] = 0;
#pragma unroll
    for (int i = 0; i < 8; ++i) { int ci = __shfl(c, i, 64); s[i + 1] = s[i] + ci; }
    int T = s[8];
    int nT = (T + 15) >> 4;

    // entry fetch: tile-entry index t -> (src, dst, e)
    auto fetch = [&](int t, int& src, int& dst, int& e) {
        if (t < T) {
            int d = 0;
#pragma unroll
            for (int i = 1; i < 8; ++i) d += (t >= s[i]);
            int2 be = bucket[(dstBase + d) * BCAP + (t - s[d])];
            src = be.x; e = be.y; dst = dstBase + d;
        } else { src = 0; dst = 0; e = -1; }
    };

    int srcA, dstA, eA, srcB, dstB, eB;
    bf16x8 gsA[4], gdA[4], gsB[4], gdB[4];
    fetch(l15, srcA, dstA, eA);
    {
        const u16* ps = gh + srcA * DH + q * 8;
        const u16* pd = gh + dstA * DH + q * 8;
#pragma unroll
        for (int kt = 0; kt < 4; ++kt) {
            gsA[kt] = *(const bf16x8*)(ps + kt * 32);
            gdA[kt] = *(const bf16x8*)(pd + kt * 32);
        }
    }
    fetch(16 + l15, srcB, dstB, eB);
    {
        const u16* ps = gh + srcB * DH + q * 8;
        const u16* pd = gh + dstB * DH + q * 8;
#pragma unroll
        for (int kt = 0; kt < 4; ++kt) {
            gsB[kt] = *(const bf16x8*)(ps + kt * 32);
            gdB[kt] = *(const bf16x8*)(pd + kt * 32);
        }
    }
    float bb2[8], owp0[8], owp1[8];
#pragma unroll
    for (int nt = 0; nt < 8; ++nt) {
        int k = nt * 16 + l15;
        bb2[nt] = b2[k];
        owp0[nt] = ow[2 * k];
        owp1[nt] = ow[2 * k + 1];
    }
    float ob0 = ob[0], ob1 = ob[1];
    __syncthreads();  // W2 staged (gathers already in flight)
    f32x4 z = {0.f, 0.f, 0.f, 0.f};

    for (int t = 0; t < nT; ++t) {
        bf16x8 fs[4], fd[4];
        int eCur;
        if (t & 1) {
#pragma unroll
            for (int kt = 0; kt < 4; ++kt) { fs[kt] = gsB[kt]; fd[kt] = gdB[kt]; }
            eCur = eB;
        } else {
#pragma unroll
            for (int kt = 0; kt < 4; ++kt) { fs[kt] = gsA[kt]; fd[kt] = gdA[kt]; }
            eCur = eA;
        }
        if (t + 2 < nT) {
            int srcN, dstN, eN;
            fetch((t + 2) * 16 + l15, srcN, dstN, eN);
            const u16* ps = gh + srcN * DH + q * 8;
            const u16* pd = gh + dstN * DH + q * 8;
            if (t & 1) {
#pragma unroll
                for (int kt = 0; kt < 4; ++kt) { gsB[kt] = *(const bf16x8*)(ps + kt * 32); gdB[kt] = *(const bf16x8*)(pd + kt * 32); }
                eB = eN;
            } else {
#pragma unroll
                for (int kt = 0; kt < 4; ++kt) { gsA[kt] = *(const bf16x8*)(ps + kt * 32); gdA[kt] = *(const bf16x8*)(pd + kt * 32); }
                eA = eN;
            }
        }
        // t1 = relu(gh_s + gh_d) directly in A-fragment layout
        bf16x8 a2[4];
#pragma unroll
        for (int kt = 0; kt < 4; ++kt) {
            bf16x8 r;
#pragma unroll
            for (int j = 0; j < 8; ++j) {
                float tt = (float)fs[kt][j] + (float)fd[kt][j];
                r[j] = (__bf16)(tt > 0.f ? tt : 0.f);
            }
            a2[kt] = r;
        }
        f32x4 acc2[8];
#pragma unroll
        for (int nt = 0; nt < 8; ++nt) acc2[nt] = z;
#pragma unroll
        for (int kt = 0; kt < 4; ++kt)
#pragma unroll
            for (int nt = 0; nt < 8; ++nt) {
                bf16x8 b = *(const bf16x8*)(wlds + (kt * 8 + nt) * 512 + lane * 8);
                acc2[nt] = mfma16(a2[kt], b, acc2[nt]);
            }
        // out layer + log_softmax; writer lane owns its row's edge id
#pragma unroll
        for (int rg = 0; rg < 4; ++rg) {
            float p0 = 0.f, p1 = 0.f;
#pragma unroll
            for (int nt = 0; nt < 8; ++nt) {
                float tt = acc2[nt][rg] + bb2[nt];
                tt = tt > 0.f ? tt : 0.f;
                p0 += tt * owp0[nt];
                p1 += tt * owp1[nt];
            }
#pragma unroll
            for (int m = 1; m < 16; m <<= 1) {
                p0 += __shfl_xor(p0, m, 64);
                p1 += __shfl_xor(p1, m, 64);
            }
            if (l15 == q * 4 + rg && eCur >= 0) {
                float s0 = p0 + ob0, s1 = p1 + ob1;
                float mx = fmaxf(s0, s1);
                float lse = mx + __logf(__expf(s0 - mx) + __expf(s1 - mx));
                outp[eCur] = make_float2(s0 - lse, s1 - lse);
            }
        }
    }
}

extern "C" void kernel_launch(void* const* d_in, const int* in_sizes, int n_in,
                              void* d_out, int out_size, void* d_ws, size_t ws_size,
                              hipStream_t stream) {
    const float* x  = (const float*)d_in[0];
    const int* ei   = (const int*)d_in[1];
    const float* wg = (const float*)d_in[2];
    const float* bg = (const float*)d_in[3];
    const float* w1 = (const float*)d_in[4];
    const float* b1 = (const float*)d_in[5];
    const float* w2 = (const float*)d_in[6];
    const float* b2 = (const float*)d_in[7];
    const float* ow = (const float*)d_in[8];
    const float* ob = (const float*)d_in[9];
    float2* out = (float2*)d_out;

    char* ws = (char*)d_ws;
    size_t off = 0;
    auto alloc = [&](size_t bytes) { void* p = ws + off; off += (bytes + 255) & ~(size_t)255; return p; };
    u16* h0      = (u16*)alloc((size_t)NN * DH * 2);   // h0pre; reused as gh
    u16* hA      = (u16*)alloc((size_t)NN * DH * 2);
    int2* bucket = (int2*)alloc((size_t)NN * BCAP * 8);
    int* cnt     = (int*)alloc((size_t)NN * 4);
    u16* w12f    = (u16*)alloc(65536);
    u16* wgf     = (u16*)alloc(65536);
    u16* gh      = h0;  // alias: h0pre dead after aggregation

    hipMemsetAsync(cnt, 0, (size_t)NN * 4, stream);
    k_prep_fill<<<32 + NE / 256, 256, 0, stream>>>(w1, w2, wg, w12f, wgf, ei, cnt, bucket);
    k_gemm_x<<<(NN + 63) / 64, 128, 0, stream>>>(x, wgf, cnt, h0);
    k_aggregate<<<NN / 4, 256, 0, stream>>>(h0, cnt, bucket, bg, hA);
    k_node_mlp<<<(NN + 127) / 128, 256, 0, stream>>>(hA, w12f, b1, b2, gh);
    k_edge_mlp<<<(NN + 31) / 32, 256, 0, stream>>>(gh, bucket, cnt, w12f, b2, ow, ob, out);
}

// Round 10
// 298.847 us; speedup vs baseline: 2.0436x; 2.0436x over previous
//
#include <hip/hip_runtime.h>

#define NN 50000
#define NE 800000
#define DIN 256
#define DH 128
#define BCAP 64

typedef float f32x4 __attribute__((ext_vector_type(4)));
typedef __bf16 bf16x8 __attribute__((ext_vector_type(8)));
typedef unsigned short u16;
typedef unsigned int u32;

__device__ __forceinline__ u16 f2b(float f) { return __builtin_bit_cast(u16, (__bf16)f); }
__device__ __forceinline__ float lo_f(u32 u) { return (float)__builtin_bit_cast(__bf16, (u16)(u & 0xFFFFu)); }
__device__ __forceinline__ float hi_f(u32 u) { return (float)__builtin_bit_cast(__bf16, (u16)(u >> 16)); }

__device__ __forceinline__ f32x4 mfma16(bf16x8 a, bf16x8 b, f32x4 c) {
    return __builtin_amdgcn_mfma_f32_16x16x32_bf16(a, b, c, 0, 0, 0);
}

// ---------------- merged: weight pre-swizzle (32 blocks) + hist + bucket fill ----------------
__global__ void k_prep_fill(const float* __restrict__ w1, const float* __restrict__ w2,
                            const float* __restrict__ wg,
                            u16* __restrict__ w12f, u16* __restrict__ wgf,
                            const int* __restrict__ ei,
                            int* __restrict__ cnt, int* __restrict__ bucket) {
    int b = blockIdx.x;
    if (b < 32) {
        int t = b * 256 + threadIdx.x;  // 0..8191
        const float* src; u16* dst; int id;
        if (t < 2048)      { src = w1; dst = w12f;          id = t; }
        else if (t < 4096) { src = w2; dst = w12f + 16384;  id = t - 2048; }
        else               { src = wg; dst = wgf;           id = t - 4096; }
        int lane = id & 63, frag = id >> 6;
        int kt = frag >> 3, nt = frag & 7;
        int k0 = kt * 32 + (lane >> 4) * 8, n = nt * 16 + (lane & 15);
        u16 v[8];
#pragma unroll
        for (int j = 0; j < 8; ++j) v[j] = f2b(src[(k0 + j) * 128 + n]);
#pragma unroll
        for (int j = 0; j < 8; ++j) dst[id * 8 + j] = v[j];
    } else {
        int e = (b - 32) * 256 + threadIdx.x;
        int d = ei[NE + e];
        int pos = atomicAdd(&cnt[d], 1);
        bucket[d * BCAP + pos] = ei[e];
    }
}

// ---------------- h0pre = (x @ W_gcn) * dinv[row]  (fp32 x -> bf16 MFMA; dinv inline) ----------------
__global__ __launch_bounds__(128) void k_gemm_x(const float* __restrict__ x,
                                                const u16* __restrict__ wgf,
                                                const int* __restrict__ cnt,
                                                u16* __restrict__ h0pre) {
    int wave = threadIdx.x >> 6, lane = threadIdx.x & 63;
    int l15 = lane & 15, q = lane >> 4;
    int rowBase = blockIdx.x * 64 + wave * 32;

    bf16x8 a[2][8];
#pragma unroll
    for (int mi = 0; mi < 2; ++mi) {
        int r = rowBase + mi * 16 + l15; if (r >= NN) r = NN - 1;
        const float* rp = x + (size_t)r * DIN + q * 8;
#pragma unroll
        for (int kt = 0; kt < 8; ++kt) {
            f32x4 f0 = *(const f32x4*)(rp + kt * 32);
            f32x4 f1 = *(const f32x4*)(rp + kt * 32 + 4);
            bf16x8 aa;
#pragma unroll
            for (int j = 0; j < 4; ++j) { aa[j] = (__bf16)f0[j]; aa[j + 4] = (__bf16)f1[j]; }
            a[mi][kt] = aa;
        }
    }
    f32x4 z = {0.f, 0.f, 0.f, 0.f};
    f32x4 acc[2][8];
#pragma unroll
    for (int mi = 0; mi < 2; ++mi)
#pragma unroll
        for (int nt = 0; nt < 8; ++nt) acc[mi][nt] = z;

#pragma unroll
    for (int kt = 0; kt < 8; ++kt)
#pragma unroll
        for (int nt = 0; nt < 8; ++nt) {
            bf16x8 b = *(const bf16x8*)(wgf + ((kt * 8 + nt) * 64 + lane) * 8);
            acc[0][nt] = mfma16(a[0][kt], b, acc[0][nt]);
            acc[1][nt] = mfma16(a[1][kt], b, acc[1][nt]);
        }
#pragma unroll
    for (int mi = 0; mi < 2; ++mi)
#pragma unroll
        for (int rg = 0; rg < 4; ++rg) {
            int r = rowBase + mi * 16 + q * 4 + rg;
            if (r < NN) {
                float dv = rsqrtf((float)cnt[r] + 1.0f);
#pragma unroll
                for (int nt = 0; nt < 8; ++nt)
                    h0pre[r * DH + nt * 16 + l15] = f2b(acc[mi][nt][rg] * dv);
            }
        }
}

// ---------------- GCN aggregate: half-wave per node, uint2 row loads, 8-deep ILP ----------------
// wave = 2 nodes; 32 lanes x 8B cover a 256B row; 16 outstanding row-gathers per wave.
__global__ __launch_bounds__(256) void k_aggregate(const u16* __restrict__ h0pre,
                                                   const int* __restrict__ cnt,
                                                   const int* __restrict__ bucket,
                                                   const float* __restrict__ bg,
                                                   u16* __restrict__ hA) {
    int wave = threadIdx.x >> 6, lane = threadIdx.x & 63;
    int hw = lane >> 5, l32 = lane & 31;
    int v = blockIdx.x * 8 + wave * 2 + hw;
    const uint2* h2p = (const uint2*)h0pre;

    uint2 su = h2p[v * 32 + l32];
    float a0[4], a1[4], a2[4], a3[4];
#pragma unroll
    for (int k = 0; k < 4; ++k) { a0[k] = 0.f; a1[k] = 0.f; a2[k] = 0.f; a3[k] = 0.f; }
    a0[0] = lo_f(su.x); a1[0] = hi_f(su.x); a2[0] = lo_f(su.y); a3[0] = hi_f(su.y);  // self-loop

    int deg = cnt[v];
    const int* bk = bucket + v * BCAP;
    int j = 0;
    for (; j + 8 <= deg; j += 8) {
        int idx[8]; uint2 u[8];
#pragma unroll
        for (int k = 0; k < 8; ++k) idx[k] = bk[j + k];
#pragma unroll
        for (int k = 0; k < 8; ++k) u[k] = h2p[idx[k] * 32 + l32];
#pragma unroll
        for (int k = 0; k < 8; ++k) {
            a0[k & 3] += lo_f(u[k].x); a1[k & 3] += hi_f(u[k].x);
            a2[k & 3] += lo_f(u[k].y); a3[k & 3] += hi_f(u[k].y);
        }
    }
    for (; j + 2 <= deg; j += 2) {
        uint2 ua = h2p[bk[j] * 32 + l32];
        uint2 ub = h2p[bk[j + 1] * 32 + l32];
        a0[0] += lo_f(ua.x); a1[0] += hi_f(ua.x); a2[0] += lo_f(ua.y); a3[0] += hi_f(ua.y);
        a0[1] += lo_f(ub.x); a1[1] += hi_f(ub.x); a2[1] += lo_f(ub.y); a3[1] += hi_f(ub.y);
    }
    for (; j < deg; ++j) {
        uint2 u = h2p[bk[j] * 32 + l32];
        a0[0] += lo_f(u.x); a1[0] += hi_f(u.x); a2[0] += lo_f(u.y); a3[0] += hi_f(u.y);
    }
    float r0 = (a0[0] + a0[1]) + (a0[2] + a0[3]);
    float r1 = (a1[0] + a1[1]) + (a1[2] + a1[3]);
    float r2 = (a2[0] + a2[1]) + (a2[2] + a2[3]);
    float r3 = (a3[0] + a3[1]) + (a3[2] + a3[3]);
    float dv = rsqrtf((float)deg + 1.0f);
    float4 bgv = ((const float4*)bg)[l32];
    r0 = fmaxf(r0 * dv + bgv.x, 0.f);
    r1 = fmaxf(r1 * dv + bgv.y, 0.f);
    r2 = fmaxf(r2 * dv + bgv.z, 0.f);
    r3 = fmaxf(r3 * dv + bgv.w, 0.f);
    uint2 outw;
    outw.x = (u32)f2b(r0) | ((u32)f2b(r1) << 16);
    outw.y = (u32)f2b(r2) | ((u32)f2b(r3) << 16);
    ((uint2*)hA)[v * 32 + l32] = outw;
}

// ---------------- fused node MLP + gh-precompute ----------------
// gh = 0.5 * (relu(relu(hA@W1+b1)@W2+b2) @ W1) + 0.5*b1   (so edge t1 = relu(gh_s + gh_d))
__global__ __launch_bounds__(256) void k_node_mlp(const u16* __restrict__ hA,
                                                  const u16* __restrict__ wf,
                                                  const float* __restrict__ b1,
                                                  const float* __restrict__ b2,
                                                  u16* __restrict__ gh) {
    __shared__ __align__(16) u16 wlds[16384];     // weight buffer (W1 -> W2 -> W1)
    __shared__ __align__(16) u16 sct[4][2176];    // per-wave transpose scratch
    {
        const uint4* s = (const uint4*)wf;
        uint4* d = (uint4*)wlds;
        for (int i = threadIdx.x; i < 2048; i += 256) d[i] = s[i];
    }
    __syncthreads();
    int wave = threadIdx.x >> 6, lane = threadIdx.x & 63;
    int l15 = lane & 15, q = lane >> 4;
    int rowBase = blockIdx.x * 128 + wave * 32;
    u16* sw = sct[wave];

    bf16x8 a[2][4];
#pragma unroll
    for (int mi = 0; mi < 2; ++mi) {
        int r = rowBase + mi * 16 + l15; if (r >= NN) r = NN - 1;
        const u16* rp = hA + r * DH + q * 8;
#pragma unroll
        for (int kt = 0; kt < 4; ++kt) a[mi][kt] = *(const bf16x8*)(rp + kt * 32);
    }
    f32x4 z = {0.f, 0.f, 0.f, 0.f};
    f32x4 acc1[2][8];
#pragma unroll
    for (int mi = 0; mi < 2; ++mi)
#pragma unroll
        for (int nt = 0; nt < 8; ++nt) acc1[mi][nt] = z;
#pragma unroll
    for (int kt = 0; kt < 4; ++kt)
#pragma unroll
        for (int nt = 0; nt < 8; ++nt) {
            bf16x8 b = *(const bf16x8*)(wlds + (kt * 8 + nt) * 512 + lane * 8);
            acc1[0][nt] = mfma16(a[0][kt], b, acc1[0][nt]);
            acc1[1][nt] = mfma16(a[1][kt], b, acc1[1][nt]);
        }
    float bb1[8], bb2[8];
#pragma unroll
    for (int nt = 0; nt < 8; ++nt) { bb1[nt] = b1[nt * 16 + l15]; bb2[nt] = b2[nt * 16 + l15]; }

    bf16x8 a2[2][4];
#pragma unroll
    for (int mi = 0; mi < 2; ++mi) {
#pragma unroll
        for (int nt = 0; nt < 8; ++nt)
#pragma unroll
            for (int rg = 0; rg < 4; ++rg) {
                float v = acc1[mi][nt][rg] + bb1[nt];
                v = v > 0.f ? v : 0.f;
                sw[(q * 4 + rg) * 136 + nt * 16 + l15] = f2b(v);
            }
#pragma unroll
        for (int kt = 0; kt < 4; ++kt)
            a2[mi][kt] = *(const bf16x8*)(sw + l15 * 136 + kt * 32 + q * 8);
    }
    __syncthreads();  // all waves done reading W1
    {
        const uint4* s = (const uint4*)(wf + 16384);
        uint4* d = (uint4*)wlds;
        for (int i = threadIdx.x; i < 2048; i += 256) d[i] = s[i];
    }
    __syncthreads();
    f32x4 acc2[2][8];
#pragma unroll
    for (int mi = 0; mi < 2; ++mi)
#pragma unroll
        for (int nt = 0; nt < 8; ++nt) acc2[mi][nt] = z;
#pragma unroll
    for (int kt = 0; kt < 4; ++kt)
#pragma unroll
        for (int nt = 0; nt < 8; ++nt) {
            bf16x8 b = *(const bf16x8*)(wlds + (kt * 8 + nt) * 512 + lane * 8);
            acc2[0][nt] = mfma16(a2[0][kt], b, acc2[0][nt]);
            acc2[1][nt] = mfma16(a2[1][kt], b, acc2[1][nt]);
        }
    bf16x8 a3[2][4];
#pragma unroll
    for (int mi = 0; mi < 2; ++mi) {
#pragma unroll
        for (int nt = 0; nt < 8; ++nt)
#pragma unroll
            for (int rg = 0; rg < 4; ++rg) {
                float v = acc2[mi][nt][rg] + bb2[nt];
                v = v > 0.f ? v : 0.f;
                sw[(q * 4 + rg) * 136 + nt * 16 + l15] = f2b(v);
            }
#pragma unroll
        for (int kt = 0; kt < 4; ++kt)
            a3[mi][kt] = *(const bf16x8*)(sw + l15 * 136 + kt * 32 + q * 8);
    }
    __syncthreads();  // all waves done reading W2
    {
        const uint4* s = (const uint4*)wf;  // reload W1
        uint4* d = (uint4*)wlds;
        for (int i = threadIdx.x; i < 2048; i += 256) d[i] = s[i];
    }
    __syncthreads();
    f32x4 acc3[2][8];
#pragma unroll
    for (int mi = 0; mi < 2; ++mi)
#pragma unroll
        for (int nt = 0; nt < 8; ++nt) acc3[mi][nt] = z;
#pragma unroll
    for (int kt = 0; kt < 4; ++kt)
#pragma unroll
        for (int nt = 0; nt < 8; ++nt) {
            bf16x8 b = *(const bf16x8*)(wlds + (kt * 8 + nt) * 512 + lane * 8);
            acc3[0][nt] = mfma16(a3[0][kt], b, acc3[0][nt]);
            acc3[1][nt] = mfma16(a3[1][kt], b, acc3[1][nt]);
        }
#pragma unroll
    for (int mi = 0; mi < 2; ++mi)
#pragma unroll
        for (int nt = 0; nt < 8; ++nt)
#pragma unroll
            for (int rg = 0; rg < 4; ++rg) {
                int r = rowBase + mi * 16 + q * 4 + rg;
                if (r < NN)
                    gh[r * DH + nt * 16 + l15] = f2b(0.5f * acc3[mi][nt][rg] + 0.5f * bb1[nt]);
            }
}

// ---------------- edge kernel (proven R5/R8 version): 64 edges/wave, t1 = relu(gh_s + gh_d) ----------------
__global__ __launch_bounds__(256, 3) void k_edge_mlp(const u16* __restrict__ gh,
                                                     const int* __restrict__ ei,
                                                     const u16* __restrict__ wf,
                                                     const float* __restrict__ b2,
                                                     const float* __restrict__ ow,
                                                     const float* __restrict__ ob,
                                                     float2* __restrict__ outp) {
    __shared__ __align__(16) u16 wlds[16384];  // W2 only
    {
        const uint4* s = (const uint4*)(wf + 16384);
        uint4* d = (uint4*)wlds;
        for (int i = threadIdx.x; i < 2048; i += 256) d[i] = s[i];
    }
    int wave = threadIdx.x >> 6, lane = threadIdx.x & 63;
    int l15 = lane & 15, q = lane >> 4;
    int eBase = blockIdx.x * 256 + wave * 64;

    int se[4], de[4];
#pragma unroll
    for (int ti = 0; ti < 4; ++ti) {
        int e = eBase + ti * 16 + l15;
        se[ti] = ei[e];
        de[ti] = ei[NE + e];
    }
    // issue gathers for first two tiles
    bf16x8 gsA[4], gdA[4], gsB[4], gdB[4];
    {
        const u16* ps = gh + se[0] * DH + q * 8;
        const u16* pd = gh + de[0] * DH + q * 8;
#pragma unroll
        for (int kt = 0; kt < 4; ++kt) {
            gsA[kt] = *(const bf16x8*)(ps + kt * 32);
            gdA[kt] = *(const bf16x8*)(pd + kt * 32);
        }
    }
    {
        const u16* ps = gh + se[1] * DH + q * 8;
        const u16* pd = gh + de[1] * DH + q * 8;
#pragma unroll
        for (int kt = 0; kt < 4; ++kt) {
            gsB[kt] = *(const bf16x8*)(ps + kt * 32);
            gdB[kt] = *(const bf16x8*)(pd + kt * 32);
        }
    }
    float bb2[8], owp0[8], owp1[8];
#pragma unroll
    for (int nt = 0; nt < 8; ++nt) {
        int k = nt * 16 + l15;
        bb2[nt] = b2[k];
        owp0[nt] = ow[2 * k];
        owp1[nt] = ow[2 * k + 1];
    }
    float ob0 = ob[0], ob1 = ob[1];
    __syncthreads();  // W2 staged (gathers already in flight)
    f32x4 z = {0.f, 0.f, 0.f, 0.f};

#pragma unroll
    for (int ti = 0; ti < 4; ++ti) {
        // current tile's fragments (A/B ping-pong), prefetch tile ti+2 into the vacated slot
        bf16x8 fs[4], fd[4];
#pragma unroll
        for (int kt = 0; kt < 4; ++kt) {
            fs[kt] = (ti & 1) ? gsB[kt] : gsA[kt];
            fd[kt] = (ti & 1) ? gdB[kt] : gdA[kt];
        }
        if (ti + 2 < 4) {
            const u16* ps = gh + se[ti + 2] * DH + q * 8;
            const u16* pd = gh + de[ti + 2] * DH + q * 8;
#pragma unroll
            for (int kt = 0; kt < 4; ++kt) {
                if (ti & 1) { gsB[kt] = *(const bf16x8*)(ps + kt * 32); gdB[kt] = *(const bf16x8*)(pd + kt * 32); }
                else        { gsA[kt] = *(const bf16x8*)(ps + kt * 32); gdA[kt] = *(const bf16x8*)(pd + kt * 32); }
            }
        }
        // t1 = relu(gh_s + gh_d) directly in A-fragment layout
        bf16x8 a2[4];
#pragma unroll
        for (int kt = 0; kt < 4; ++kt) {
            bf16x8 r;
#pragma unroll
            for (int j = 0; j < 8; ++j) {
                float t = (float)fs[kt][j] + (float)fd[kt][j];
                r[j] = (__bf16)(t > 0.f ? t : 0.f);
            }
            a2[kt] = r;
        }
        f32x4 acc2[8];
#pragma unroll
        for (int nt = 0; nt < 8; ++nt) acc2[nt] = z;
#pragma unroll
        for (int kt = 0; kt < 4; ++kt)
#pragma unroll
            for (int nt = 0; nt < 8; ++nt) {
                bf16x8 b = *(const bf16x8*)(wlds + (kt * 8 + nt) * 512 + lane * 8);
                acc2[nt] = mfma16(a2[kt], b, acc2[nt]);
            }
        // out layer + log_softmax
#pragma unroll
        for (int rg = 0; rg < 4; ++rg) {
            float p0 = 0.f, p1 = 0.f;
#pragma unroll
            for (int nt = 0; nt < 8; ++nt) {
                float t = acc2[nt][rg] + bb2[nt];
                t = t > 0.f ? t : 0.f;
                p0 += t * owp0[nt];
                p1 += t * owp1[nt];
            }
#pragma unroll
            for (int m = 1; m < 16; m <<= 1) {
                p0 += __shfl_xor(p0, m, 64);
                p1 += __shfl_xor(p1, m, 64);
            }
            if (l15 == 0) {
                int e = eBase + ti * 16 + q * 4 + rg;
                float s0 = p0 + ob0, s1 = p1 + ob1;
                float mx = fmaxf(s0, s1);
                float lse = mx + __logf(__expf(s0 - mx) + __expf(s1 - mx));
                outp[e] = make_float2(s0 - lse, s1 - lse);
            }
        }
    }
}

extern "C" void kernel_launch(void* const* d_in, const int* in_sizes, int n_in,
                              void* d_out, int out_size, void* d_ws, size_t ws_size,
                              hipStream_t stream) {
    const float* x  = (const float*)d_in[0];
    const int* ei   = (const int*)d_in[1];
    const float* wg = (const float*)d_in[2];
    const float* bg = (const float*)d_in[3];
    const float* w1 = (const float*)d_in[4];
    const float* b1 = (const float*)d_in[5];
    const float* w2 = (const float*)d_in[6];
    const float* b2 = (const float*)d_in[7];
    const float* ow = (const float*)d_in[8];
    const float* ob = (const float*)d_in[9];
    float2* out = (float2*)d_out;

    char* ws = (char*)d_ws;
    size_t off = 0;
    auto alloc = [&](size_t bytes) { void* p = ws + off; off += (bytes + 255) & ~(size_t)255; return p; };
    u16* h0      = (u16*)alloc((size_t)NN * DH * 2);   // h0pre; reused as gh
    u16* hA      = (u16*)alloc((size_t)NN * DH * 2);
    int* bucket  = (int*)alloc((size_t)NN * BCAP * 4);
    int* cnt     = (int*)alloc((size_t)NN * 4);
    u16* w12f    = (u16*)alloc(65536);
    u16* wgf     = (u16*)alloc(65536);
    u16* gh      = h0;  // alias: h0pre dead after aggregation

    hipMemsetAsync(cnt, 0, (size_t)NN * 4, stream);
    k_prep_fill<<<32 + NE / 256, 256, 0, stream>>>(w1, w2, wg, w12f, wgf, ei, cnt, bucket);
    k_gemm_x<<<(NN + 63) / 64, 128, 0, stream>>>(x, wgf, cnt, h0);
    k_aggregate<<<NN / 8, 256, 0, stream>>>(h0, cnt, bucket, bg, hA);
    k_node_mlp<<<(NN + 127) / 128, 256, 0, stream>>>(hA, w12f, b1, b2, gh);
    k_edge_mlp<<<NE / 256, 256, 0, stream>>>(gh, ei, w12f, b2, ow, ob, out);
}